// Round 7
// baseline (3284.700 us; speedup 1.0000x reference)
//
#include <hip/hip_runtime.h>
#include <hip/hip_bf16.h>
#include <cstdint>
#include <cstddef>

typedef __bf16 bf16_t;
typedef __bf16 bf16x8 __attribute__((ext_vector_type(8)));
typedef float  f32x4  __attribute__((ext_vector_type(4)));

#define NB 64      // batch
#define NS 512     // source sequence length
#define NTD 128    // decoder steps
#define NE 256     // embedding dim
#define NH 512     // hidden dim
#define NG 2048    // 4*H (gates)
#define NW 256     // attention width

// one timestep of h in fragment layout = [4 bg][16 ks][64 lanes][4 dwords]
#define HSTEP_DW 16384u
#define FPAD 16    // flag padding (dwords) = 64B -> one line per flag

__device__ __forceinline__ float sigm_f(float x) { return 1.f / (1.f + __expf(-x)); }
__device__ __forceinline__ float tanh_f(float x) {
  float e = __expf(2.f * x);
  return 1.f - 2.f / (e + 1.f);
}
__device__ __forceinline__ float bits2f(uint32_t b16) {
  uint32_t u = b16 << 16;
  return __builtin_bit_cast(float, u);
}
__device__ __forceinline__ uint32_t aload(const uint32_t* p) {
  return __hip_atomic_load(p, __ATOMIC_RELAXED, __HIP_MEMORY_SCOPE_AGENT);
}
__device__ __forceinline__ uint64_t aload64(const uint64_t* p) {
  return __hip_atomic_load(p, __ATOMIC_RELAXED, __HIP_MEMORY_SCOPE_AGENT);
}
__device__ __forceinline__ void astore(uint32_t* p, uint32_t v) {
  __hip_atomic_store(p, v, __ATOMIC_RELAXED, __HIP_MEMORY_SCOPE_AGENT);
}
__device__ __forceinline__ void astoref(float* p, float v) {
  __hip_atomic_store((uint32_t*)p, __builtin_bit_cast(uint32_t, v),
                     __ATOMIC_RELAXED, __HIP_MEMORY_SCOPE_AGENT);
}
__device__ __forceinline__ float aloadf(const float* p) {
  return __builtin_bit_cast(float, aload((const uint32_t*)p));
}
__device__ __forceinline__ void drain_vm() {
  asm volatile("s_waitcnt vmcnt(0)" ::: "memory");
}
// pick fp32 from packed 4x bf16 (uint2), r in [0,4)
__device__ __forceinline__ float xpick(uint2 v, int r) {
  uint32_t d = (r < 2) ? v.x : v.y;
  return bits2f((r & 1) ? (d >> 16) : (d & 0xffffu));
}

// Pack fp32 weight W[N][K] (used as B[k][n] = W[n][k]) into per-lane MFMA
// B-fragment order: dst[((ntile*(K/32)+kstep)*64 + lane)*8 + j]
__global__ __launch_bounds__(256) void pack_b(const float* __restrict__ src,
                                              bf16_t* __restrict__ dst,
                                              int N, int K) {
  int idx = blockIdx.x * 256 + threadIdx.x;
  if (idx >= N * K) return;
  int n = idx / K, k = idx - n * K;
  int lane = (((k & 31) >> 3) << 4) | (n & 15);
  size_t o = ((((size_t)(n >> 4) * (K >> 5)) + (k >> 5)) * 64 + lane) * 8 + (k & 7);
  dst[o] = (bf16_t)src[idx];
}

// Embedding gather writing A-FRAGMENT layout.
__global__ __launch_bounds__(256) void gather_emb(const int* __restrict__ tokens,
                                                  const float* __restrict__ table,
                                                  bf16_t* __restrict__ embfrag) {
  int idx = blockIdx.x * 256 + threadIdx.x;    // over (NS*NB)*(NE/8)
  int row = idx >> 5, e0 = (idx & 31) << 3;
  int b = row & 63, s = row >> 6;
  int tok = tokens[b * NS + s];
  const float4* p = (const float4*)(table + (size_t)tok * NE + e0);
  float4 v0 = p[0], v1 = p[1];
  bf16x8 v;
  v[0] = (bf16_t)v0.x; v[1] = (bf16_t)v0.y; v[2] = (bf16_t)v0.z; v[3] = (bf16_t)v0.w;
  v[4] = (bf16_t)v1.x; v[5] = (bf16_t)v1.y; v[6] = (bf16_t)v1.z; v[7] = (bf16_t)v1.w;
  int mt = row >> 4;
  int ks = e0 >> 5;
  int lane = (b & 15) | (((e0 >> 3) & 3) << 4);
  *(bf16x8*)(embfrag + ((size_t)(mt * 8 + ks) * 64 + lane) * 8) = v;
}

// dec_h0 fp32 [64][512] -> fragment layout dword buffer (step 0 of dec hfrag)
__global__ __launch_bounds__(256) void pack_h0(const float* __restrict__ src,
                                               uint32_t* __restrict__ dst) {
  int idx = blockIdx.x * 256 + threadIdx.x;  // 0..16383 (dword id)
  int b = idx >> 8, jp = idx & 255;
  int j = jp * 2;
  float lo = src[(size_t)b * NH + j], hi = src[(size_t)b * NH + j + 1];
  uint16_t l16 = __builtin_bit_cast(uint16_t, (bf16_t)lo);
  uint16_t h16 = __builtin_bit_cast(uint16_t, (bf16_t)hi);
  int bg = b >> 4, bl = b & 15, ks = j >> 5;
  int lane = bl | (((j >> 3) & 3) << 4);
  dst[((size_t)bg * 16 + ks) * 256 + lane * 4 + ((j >> 1) & 3)] =
      (uint32_t)l16 | ((uint32_t)h16 << 16);
}

// Xih GEMM writing the CHAIN-CONSUMPTION layout:
// block = ((mt*16 + slice)*2 + ct)*4 + g ; addr_bf16 = block*256 + lane*4 + r
// (mt = t*4+bg; per lane 4 bf16 = 8B dense; per wave 512B contiguous)
__global__ __launch_bounds__(256) void gemm_xih(const bf16_t* __restrict__ A,
                                                const bf16_t* __restrict__ Bp,
                                                bf16_t* __restrict__ out,
                                                const float* __restrict__ b1,
                                                const float* __restrict__ b2) {
  const int KS = 8, MT = 16;
  int lane = threadIdx.x & 63, w = threadIdx.x >> 6;
  int nt = blockIdx.x * 4 + w;        // 0..127
  int mt0 = blockIdx.y * MT;
  bf16x8 bfr[KS];
  const bf16_t* bp = Bp + ((size_t)nt * KS * 64 + lane) * 8;
#pragma unroll
  for (int ks = 0; ks < KS; ++ks) bfr[ks] = *(const bf16x8*)(bp + (size_t)ks * 512);
  int n = (nt << 4) + (lane & 15);
  float bs = b1[n] + b2[n];
  int g = nt >> 5, sl = (nt & 31) >> 1, ct = nt & 1;
  for (int m = 0; m < MT; ++m) {
    int mt = mt0 + m;
    const bf16_t* ap = A + (size_t)mt * (KS * 512) + lane * 8;
    f32x4 acc = {0.f, 0.f, 0.f, 0.f};
#pragma unroll
    for (int ks = 0; ks < KS; ++ks)
      acc = __builtin_amdgcn_mfma_f32_16x16x32_bf16(
          *(const bf16x8*)(ap + (size_t)ks * 512), bfr[ks], acc, 0, 0, 0);
    ushort4 hv;
    hv.x = __builtin_bit_cast(uint16_t, (bf16_t)(acc[0] + bs));
    hv.y = __builtin_bit_cast(uint16_t, (bf16_t)(acc[1] + bs));
    hv.z = __builtin_bit_cast(uint16_t, (bf16_t)(acc[2] + bs));
    hv.w = __builtin_bit_cast(uint16_t, (bf16_t)(acc[3] + bs));
    *(ushort4*)(out + ((((size_t)mt * 16 + sl) * 2 + ct) * 4 + g) * 256 + lane * 4) = hv;
  }
}

// ---------------- encoder chain: barrier-free, wave-local gates ----------
// 64 WGs x 256: bg = blockIdx>>4, slice = blockIdx&15. Waves 0,1 = chain
// (col-tile ct = wave id; each computes ALL 4 gates for its 16 cols -> cell
// update wave-local, no LDS exchange, no __syncthreads in loop). Wave 2 =
// trailing blend1 GEMM (off critical path). Wave 3 stages LDS then exits.
// Per-wave flags (64B padded): store h -> s_waitcnt vmcnt(0) -> flag.
__global__ __launch_bounds__(256) void enc_chain(
    const bf16_t* __restrict__ Wp, const bf16_t* __restrict__ xih2,
    const bf16_t* __restrict__ W1p, const float* __restrict__ W1_b,
    uint32_t* __restrict__ hfrag, uint32_t* __restrict__ flags,
    bf16_t* __restrict__ blend1) {
  __shared__ bf16_t wlds[8 * 8192];   // [g*2+ct][16ks][64][8]
  __shared__ bf16_t wb[8192];         // W1 n-tile 'slice'
  int tid = threadIdx.x, lane = tid & 63, wid = tid >> 6;
  int bg = blockIdx.x >> 4, slice = blockIdx.x & 15;

  for (int l = 0; l < 8; ++l) {
    int g = l >> 1, p = l & 1;
    const bf16_t* s = Wp + (size_t)(g * 32 + slice * 2 + p) * 8192;
    for (int i = tid; i < 1024; i += 256)
      *(bf16x8*)(wlds + l * 8192 + (size_t)i * 8) = *(const bf16x8*)(s + (size_t)i * 8);
  }
  {
    const bf16_t* s = W1p + (size_t)slice * 8192;
    for (int i = tid; i < 1024; i += 256)
      *(bf16x8*)(wb + (size_t)i * 8) = *(const bf16x8*)(s + (size_t)i * 8);
  }
  __syncthreads();
  if (wid == 3) return;

  const uint64_t* hq = (const uint64_t*)hfrag;
  uint32_t* fbase = flags + bg * 32 * FPAD;
  int c = lane & 15, grp = lane >> 4;

  if (wid < 2) {
    int ct = wid;
    int j = slice * 32 + ct * 16 + c;
    int sub = (j >> 3) & 3, dw = (j >> 1) & 3;
    uint32_t* myflag = fbase + (slice * 2 + ct) * FPAD;
    float cst[4] = {0.f, 0.f, 0.f, 0.f};
    const bf16_t* wb0 = wlds + (size_t)(0 * 2 + ct) * 8192;
    const bf16_t* wb1 = wlds + (size_t)(1 * 2 + ct) * 8192;
    const bf16_t* wb2 = wlds + (size_t)(2 * 2 + ct) * 8192;
    const bf16_t* wb3 = wlds + (size_t)(3 * 2 + ct) * 8192;
    for (int t = 0; t < NS; ++t) {
      // xih prefetch (latency hides under poll)
      const uint32_t* xb = (const uint32_t*)xih2 +
          ((((size_t)t * 4 + bg) * 16 + slice) * 2 + ct) * 512 + lane * 2;
      uint2 xg0 = *(const uint2*)(xb);
      uint2 xg1 = *(const uint2*)(xb + 128);
      uint2 xg2 = *(const uint2*)(xb + 256);
      uint2 xg3 = *(const uint2*)(xb + 384);
      if (t > 0) {
        uint32_t tgt = (uint32_t)t; bool ok;
        do {
          uint32_t f = tgt;
          if (lane < 32) f = aload(fbase + lane * FPAD);
          ok = __all(f >= tgt);
        } while (!ok);
      }
      const uint64_t* hb = hq + ((size_t)t * 4 + bg) * 2048 + lane * 2;
      uint64_t aq[16][2];
#pragma unroll
      for (int ks = 0; ks < 16; ++ks) {
        aq[ks][0] = aload64(hb + (size_t)ks * 128);
        aq[ks][1] = aload64(hb + (size_t)ks * 128 + 1);
      }
      f32x4 a0 = {0.f,0.f,0.f,0.f}, a1 = a0, a2 = a0, a3 = a0;
#pragma unroll
      for (int ks = 0; ks < 16; ++ks) {
        union { uint64_t q[2]; bf16x8 v; } u;
        u.q[0] = aq[ks][0]; u.q[1] = aq[ks][1];
        int o = ks * 512 + lane * 8;
        a0 = __builtin_amdgcn_mfma_f32_16x16x32_bf16(u.v, *(const bf16x8*)(wb0 + o), a0, 0, 0, 0);
        a1 = __builtin_amdgcn_mfma_f32_16x16x32_bf16(u.v, *(const bf16x8*)(wb1 + o), a1, 0, 0, 0);
        a2 = __builtin_amdgcn_mfma_f32_16x16x32_bf16(u.v, *(const bf16x8*)(wb2 + o), a2, 0, 0, 0);
        a3 = __builtin_amdgcn_mfma_f32_16x16x32_bf16(u.v, *(const bf16x8*)(wb3 + o), a3, 0, 0, 0);
      }
      uint32_t hsb = ((uint32_t)(t + 1) * 4 + (uint32_t)bg) * 4096 + slice * 256;
#pragma unroll
      for (int r = 0; r < 4; ++r) {
        float pi = a0[r] + xpick(xg0, r), pf = a1[r] + xpick(xg1, r);
        float pg = a2[r] + xpick(xg2, r), po = a3[r] + xpick(xg3, r);
        float iG = sigm_f(pi), fG = sigm_f(pf), gG = tanh_f(pg), oG = sigm_f(po);
        cst[r] = fG * cst[r] + iG * gG;
        float h = oG * tanh_f(cst[r]);
        uint16_t hv = __builtin_bit_cast(uint16_t, (bf16_t)h);
        uint32_t other = (uint32_t)__shfl_xor((int)(uint32_t)hv, 1, 64);
        if (!(lane & 1)) {   // even col stores packed (j, j+1) dword
          uint32_t dword = (uint32_t)hv | (other << 16);
          astore(hfrag + (size_t)hsb + (((grp * 4 + r) | (sub << 4)) * 4 + dw), dword);
        }
      }
      drain_vm();                     // h stores ACKed at L3
      if (lane == 0) astore(myflag, (uint32_t)(t + 1));
    }
  } else {
    // wave 2: trailing blend1[t-1] = h_t @ W1slice + b
    float bb = W1_b[slice * 16 + c];
    for (int t = 1; t <= NS; ++t) {
      uint32_t tgt = (uint32_t)t; bool ok;
      do {
        uint32_t f = tgt;
        if (lane < 32) f = aload(fbase + lane * FPAD);
        ok = __all(f >= tgt);
      } while (!ok);
      const uint64_t* hb = hq + ((size_t)t * 4 + bg) * 2048 + lane * 2;
      f32x4 acc = {0.f, 0.f, 0.f, 0.f};
#pragma unroll
      for (int ks = 0; ks < 16; ++ks) {
        union { uint64_t q[2]; bf16x8 v; } u;
        u.q[0] = aload64(hb + (size_t)ks * 128);
        u.q[1] = aload64(hb + (size_t)ks * 128 + 1);
        acc = __builtin_amdgcn_mfma_f32_16x16x32_bf16(
            u.v, *(const bf16x8*)(wb + ks * 512 + lane * 8), acc, 0, 0, 0);
      }
      size_t row = (size_t)(t - 1) * 64 + bg * 16 + grp * 4;
#pragma unroll
      for (int r = 0; r < 4; ++r)
        blend1[(row + r) * 256 + slice * 16 + c] = (bf16_t)(acc[r] + bb);
    }
  }
}

// -------- decoder chain (same structure) + blend2 wave + attn workers -----
__global__ __launch_bounds__(256) void dec_attn(
    const bf16_t* __restrict__ Wp, const float* __restrict__ bih,
    const float* __restrict__ bhh, const bf16_t* __restrict__ W2p,
    const float* __restrict__ W2_b, uint32_t* __restrict__ hfrag,
    const uint32_t* __restrict__ c0frag, uint32_t* __restrict__ dflags,
    uint32_t* __restrict__ bl2f, const bf16_t* __restrict__ blend1,
    float* __restrict__ blend2, const float* __restrict__ vt_w,
    float* __restrict__ out) {
  union SM {
    struct { bf16_t wlds[8 * 8192]; bf16_t wb[8192]; } c;
    struct { float vt[272], b2[272], u[512], red[8]; } a;
  };
  __shared__ SM sm;
  int tid = threadIdx.x, lane = tid & 63, wid = tid >> 6;

  if (blockIdx.x < 64) {
    int bg = blockIdx.x >> 4, slice = blockIdx.x & 15;
    for (int l = 0; l < 8; ++l) {
      int g = l >> 1, p = l & 1;
      const bf16_t* s = Wp + (size_t)(g * 32 + slice * 2 + p) * 8192;
      for (int i = tid; i < 1024; i += 256)
        *(bf16x8*)(sm.c.wlds + l * 8192 + (size_t)i * 8) = *(const bf16x8*)(s + (size_t)i * 8);
    }
    {
      const bf16_t* s = W2p + (size_t)slice * 8192;
      for (int i = tid; i < 1024; i += 256)
        *(bf16x8*)(sm.c.wb + (size_t)i * 8) = *(const bf16x8*)(s + (size_t)i * 8);
    }
    __syncthreads();
    if (wid == 3) return;

    const uint64_t* hq = (const uint64_t*)hfrag;
    uint32_t* fbase = dflags + bg * 32 * FPAD;
    int c = lane & 15, grp = lane >> 6 ? 0 : lane >> 4;  // grp = lane>>4
    grp = lane >> 4;

    if (wid < 2) {
      int ct = wid;
      int j = slice * 32 + ct * 16 + c;
      int sub = (j >> 3) & 3, dw = (j >> 1) & 3, half = j & 1;
      uint32_t* myflag = fbase + (slice * 2 + ct) * FPAD;
      float bs0 = bih[0 * NH + j] + bhh[0 * NH + j];
      float bs1 = bih[1 * NH + j] + bhh[1 * NH + j];
      float bs2 = bih[2 * NH + j] + bhh[2 * NH + j];
      float bs3 = bih[3 * NH + j] + bhh[3 * NH + j];
      float cst[4];
#pragma unroll
      for (int r = 0; r < 4; ++r) {
        uint32_t d = c0frag[(size_t)(bg * 16 + slice) * 256 +
                            (((grp * 4 + r) | (sub << 4)) * 4 + dw)];
        cst[r] = half ? bits2f(d >> 16) : bits2f(d & 0xffffu);
      }
      const bf16_t* wb0 = sm.c.wlds + (size_t)(0 * 2 + ct) * 8192;
      const bf16_t* wb1 = sm.c.wlds + (size_t)(1 * 2 + ct) * 8192;
      const bf16_t* wb2 = sm.c.wlds + (size_t)(2 * 2 + ct) * 8192;
      const bf16_t* wb3 = sm.c.wlds + (size_t)(3 * 2 + ct) * 8192;
      for (int t = 0; t < NTD; ++t) {
        if (t > 0) {
          uint32_t tgt = (uint32_t)t; bool ok;
          do {
            uint32_t f = tgt;
            if (lane < 32) f = aload(fbase + lane * FPAD);
            ok = __all(f >= tgt);
          } while (!ok);
        }
        const uint64_t* hb = hq + ((size_t)t * 4 + bg) * 2048 + lane * 2;
        uint64_t aq[16][2];
#pragma unroll
        for (int ks = 0; ks < 16; ++ks) {
          aq[ks][0] = aload64(hb + (size_t)ks * 128);
          aq[ks][1] = aload64(hb + (size_t)ks * 128 + 1);
        }
        f32x4 a0 = {0.f,0.f,0.f,0.f}, a1 = a0, a2 = a0, a3 = a0;
#pragma unroll
        for (int ks = 0; ks < 16; ++ks) {
          union { uint64_t q[2]; bf16x8 v; } u;
          u.q[0] = aq[ks][0]; u.q[1] = aq[ks][1];
          int o = ks * 512 + lane * 8;
          a0 = __builtin_amdgcn_mfma_f32_16x16x32_bf16(u.v, *(const bf16x8*)(wb0 + o), a0, 0, 0, 0);
          a1 = __builtin_amdgcn_mfma_f32_16x16x32_bf16(u.v, *(const bf16x8*)(wb1 + o), a1, 0, 0, 0);
          a2 = __builtin_amdgcn_mfma_f32_16x16x32_bf16(u.v, *(const bf16x8*)(wb2 + o), a2, 0, 0, 0);
          a3 = __builtin_amdgcn_mfma_f32_16x16x32_bf16(u.v, *(const bf16x8*)(wb3 + o), a3, 0, 0, 0);
        }
        uint32_t hsb = ((uint32_t)(t + 1) * 4 + (uint32_t)bg) * 4096 + slice * 256;
#pragma unroll
        for (int r = 0; r < 4; ++r) {
          float iG = sigm_f(a0[r] + bs0), fG = sigm_f(a1[r] + bs1);
          float gG = tanh_f(a2[r] + bs2), oG = sigm_f(a3[r] + bs3);
          cst[r] = fG * cst[r] + iG * gG;
          float h = oG * tanh_f(cst[r]);
          uint16_t hv = __builtin_bit_cast(uint16_t, (bf16_t)h);
          uint32_t other = (uint32_t)__shfl_xor((int)(uint32_t)hv, 1, 64);
          if (!(lane & 1)) {
            uint32_t dword = (uint32_t)hv | (other << 16);
            astore(hfrag + (size_t)hsb + (((grp * 4 + r) | (sub << 4)) * 4 + dw), dword);
          }
        }
        drain_vm();
        if (lane == 0) astore(myflag, (uint32_t)(t + 1));
      }
    } else {
      // wave 2: trailing blend2[t-1] (fp32, agent stores) + bl2f flags
      float bb = W2_b[slice * 16 + c];
      uint32_t* myb = bl2f + (bg * 16 + slice) * FPAD;
      for (int t = 1; t <= NTD; ++t) {
        uint32_t tgt = (uint32_t)t; bool ok;
        do {
          uint32_t f = tgt;
          if (lane < 32) f = aload(fbase + lane * FPAD);
          ok = __all(f >= tgt);
        } while (!ok);
        const uint64_t* hb = hq + ((size_t)t * 4 + bg) * 2048 + lane * 2;
        f32x4 acc = {0.f, 0.f, 0.f, 0.f};
#pragma unroll
        for (int ks = 0; ks < 16; ++ks) {
          union { uint64_t q[2]; bf16x8 v; } u;
          u.q[0] = aload64(hb + (size_t)ks * 128);
          u.q[1] = aload64(hb + (size_t)ks * 128 + 1);
          acc = __builtin_amdgcn_mfma_f32_16x16x32_bf16(
              u.v, *(const bf16x8*)(sm.c.wb + ks * 512 + lane * 8), acc, 0, 0, 0);
        }
        size_t row = (size_t)(t - 1) * 64 + bg * 16 + grp * 4;
#pragma unroll
        for (int r = 0; r < 4; ++r)
          astoref(blend2 + (row + r) * 256 + slice * 16 + c, acc[r] + bb);
        drain_vm();
        if (lane == 0) astore(myb, (uint32_t)t);
      }
    }
  } else {
    // ---------------- attention workers ----------------
    int w = blockIdx.x - 64;   // 0..191
    for (int k = w; k < NTD * NB; k += 192) {
      int t = k >> 6, b = k & 63, bgb = b >> 4;
      if (wid == 0) {
        uint32_t tgt = (uint32_t)(t + 1); bool ok;
        do {
          uint32_t f = tgt;
          if (lane < 16) f = aload(bl2f + (bgb * 16 + lane) * FPAD);
          ok = __all(f >= tgt);
          if (!ok) __builtin_amdgcn_s_sleep(16);
        } while (!ok);
      }
      __syncthreads();
      {
        int ww = tid;
        int pi = ww + ((ww >> 6) << 2);
        sm.a.vt[pi] = vt_w[ww];
        sm.a.b2[pi] = aloadf(blend2 + (size_t)(t * 64 + b) * NW + ww);
      }
      __syncthreads();
      int wgrp = lane >> 4, sgrp = lane & 15;
      int base = wgrp * 68;
      for (int it = 0; it < 8; ++it) {
        int s = it * 64 + wid * 16 + sgrp;
        const bf16_t* row = blend1 + ((size_t)s * NB + b) * NW + wgrp * 64;
        float val = 0.f;
#pragma unroll
        for (int c8 = 0; c8 < 8; ++c8) {
          bf16x8 v = *(const bf16x8*)(row + c8 * 8);
#pragma unroll
          for (int jx = 0; jx < 8; ++jx) {
            int wi = base + c8 * 8 + jx;
            val += sm.a.vt[wi] * tanh_f((float)v[jx] + sm.a.b2[wi]);
          }
        }
        val += __shfl_xor(val, 16, 64);
        val += __shfl_xor(val, 32, 64);
        if (wgrp == 0) sm.a.u[it * 64 + wid * 16 + sgrp] = val;
      }
      __syncthreads();
      float a = sm.a.u[tid], bb2 = sm.a.u[tid + 256];
      float m = fmaxf(a, bb2);
#pragma unroll
      for (int o = 1; o < 64; o <<= 1) m = fmaxf(m, __shfl_xor(m, o, 64));
      if (lane == 0) sm.a.red[wid] = m;
      __syncthreads();
      m = fmaxf(fmaxf(sm.a.red[0], sm.a.red[1]), fmaxf(sm.a.red[2], sm.a.red[3]));
      float e = __expf(a - m) + __expf(bb2 - m);
#pragma unroll
      for (int o = 1; o < 64; o <<= 1) e += __shfl_xor(e, o, 64);
      if (lane == 0) sm.a.red[4 + wid] = e;
      __syncthreads();
      float lz = m + logf(sm.a.red[4] + sm.a.red[5] + sm.a.red[6] + sm.a.red[7]);
      size_t ob = ((size_t)b * NTD + t) * NS;
      out[ob + tid] = a - lz;
      out[ob + tid + 256] = bb2 - lz;
      __syncthreads();
    }
  }
}

extern "C" void kernel_launch(void* const* d_in, const int* in_sizes, int n_in,
                              void* d_out, int out_size, void* d_ws, size_t ws_size,
                              hipStream_t stream) {
  const int*   tokens    = (const int*)d_in[0];
  const float* dec_h0    = (const float*)d_in[1];
  const float* emb_table = (const float*)d_in[2];
  const float* enc_Wih   = (const float*)d_in[3];
  const float* enc_Whh   = (const float*)d_in[4];
  const float* enc_bih   = (const float*)d_in[5];
  const float* enc_bhh   = (const float*)d_in[6];
  // d_in[7] = dec_Wih: unused (decoder input is the zero vector)
  const float* dec_Whh   = (const float*)d_in[8];
  const float* dec_bih   = (const float*)d_in[9];
  const float* dec_bhh   = (const float*)d_in[10];
  const float* W1_w      = (const float*)d_in[11];
  const float* W1_b      = (const float*)d_in[12];
  const float* W2_w      = (const float*)d_in[13];
  const float* W2_b      = (const float*)d_in[14];
  const float* vt_w      = (const float*)d_in[15];
  // d_in[16] = vt_b: constant shift, invariant under log_softmax
  float* out = (float*)d_out;

  char* w = (char*)d_ws;
  size_t off = 0;
  auto alloc = [&](size_t bytes) {
    size_t o = off;
    off += (bytes + 255) & ~(size_t)255;
    return o;
  };
  bf16_t* embfrag = (bf16_t*)(w + alloc((size_t)NS * NB * NE * 2));           // 16.8 MB
  bf16_t* xih2    = (bf16_t*)(w + alloc((size_t)NS * NB * NG * 2));           // 134 MB
  uint32_t* enc_hf = (uint32_t*)(w + alloc((size_t)(NS + 1) * HSTEP_DW * 4)); // 33.6 MB
  uint32_t* dec_hf = (uint32_t*)(w + alloc((size_t)(NTD + 1) * HSTEP_DW * 4)); // 8.5 MB
  bf16_t* blend1  = (bf16_t*)(w + alloc((size_t)NS * NB * NW * 2));           // 16.8 MB
  float*  blend2  = (float*)(w + alloc((size_t)NTD * NB * NW * 4));           // 8.4 MB
  bf16_t* pWih    = (bf16_t*)(w + alloc((size_t)NG * NE * 2));
  bf16_t* pWhhE   = (bf16_t*)(w + alloc((size_t)NG * NH * 2));
  bf16_t* pWhhD   = (bf16_t*)(w + alloc((size_t)NG * NH * 2));
  bf16_t* pW1     = (bf16_t*)(w + alloc((size_t)NW * NH * 2));
  bf16_t* pW2     = (bf16_t*)(w + alloc((size_t)NW * NH * 2));
  uint32_t* flags = (uint32_t*)(w + alloc(5120 * 4));  // enc 2048 | dec 2048 | bl2f 1024
  (void)ws_size; (void)in_sizes; (void)n_in; (void)out_size;

  hipMemsetAsync(flags, 0, 5120 * 4, stream);
  hipMemsetAsync(enc_hf, 0, HSTEP_DW * 4, stream);

  pack_b<<<(NG * NE) / 256, 256, 0, stream>>>(enc_Wih, pWih, NG, NE);
  pack_b<<<(NG * NH) / 256, 256, 0, stream>>>(enc_Whh, pWhhE, NG, NH);
  pack_b<<<(NG * NH) / 256, 256, 0, stream>>>(dec_Whh, pWhhD, NG, NH);
  pack_b<<<(NW * NH) / 256, 256, 0, stream>>>(W1_w, pW1, NW, NH);
  pack_b<<<(NW * NH) / 256, 256, 0, stream>>>(W2_w, pW2, NW, NH);

  gather_emb<<<(NS * NB * (NE / 8)) / 256, 256, 0, stream>>>(tokens, emb_table, embfrag);
  pack_h0<<<64, 256, 0, stream>>>(dec_h0, dec_hf);

  // Xih = emb @ Wih.T + bih + bhh  (chain-consumption layout)
  gemm_xih<<<dim3(128 / 4, 2048 / 16), 256, 0, stream>>>(
      embfrag, pWih, xih2, enc_bih, enc_bhh);

  // encoder chain + trailing blend1 wave
  enc_chain<<<64, 256, 0, stream>>>(pWhhE, xih2, pW1, W1_b, enc_hf, flags, blend1);

  // decoder chain + trailing blend2 wave + overlapped attention workers
  dec_attn<<<256, 256, 0, stream>>>(pWhhD, dec_bih, dec_bhh, pW2, W2_b, dec_hf,
                                    enc_hf + (size_t)NS * HSTEP_DW,
                                    flags + 2048, flags + 4096,
                                    blend1, blend2, vt_w, out);
}